// Round 1
// baseline (220.885 us; speedup 1.0000x reference)
//
#include <hip/hip_runtime.h>
#include <hip/hip_bf16.h>
#include <math.h>

#define EPSV 1e-8f

__device__ __forceinline__ float wsum64(float v) {
#pragma unroll
  for (int m = 1; m <= 32; m <<= 1) v += __shfl_xor(v, m);
  return v;
}
__device__ __forceinline__ float wmax64(float v) {
#pragma unroll
  for (int m = 1; m <= 32; m <<= 1) v = fmaxf(v, __shfl_xor(v, m));
  return v;
}
__device__ __forceinline__ float wmin64(float v) {
#pragma unroll
  for (int m = 1; m <= 32; m <<= 1) v = fminf(v, __shfl_xor(v, m));
  return v;
}

// One workgroup per (b, s, n): 4096 blocks x 256 threads.
__global__ __launch_bounds__(256, 2) void stage1_kernel(
    const float* __restrict__ sat, float* __restrict__ node,
    float* __restrict__ edge, float* __restrict__ score) {
  const int bid = blockIdx.x;
  const int n = bid & 63;
  // s = (bid >> 6) & 3, b = bid >> 8; t-base = b*256 + s*64
  const int tbase = (bid >> 6) * 64;  // (b*4+s)*64 == b*256 + s*64
  const int bs = bid >> 6;

  __shared__ float Ps[64][64];
  __shared__ float ent_s[64];
  __shared__ float diff_s[64];
  __shared__ float psum_s[4][64];
  __shared__ float dsq_s[4][64];

  const int tid = threadIdx.x;
  const int wave = tid >> 6;
  const int lane = tid & 63;
  const int q = lane >> 4;   // head sub-group 0..3
  const int r = lane & 15;   // 4-float chunk within row

  // ---- phase 1: softmax over j (64), mean over h (8) -> Ps[l][j] ----
  const size_t tstride = 8ull * 64 * 64;  // floats per t
  const float* basep = sat + (size_t)tbase * tstride + (size_t)n * 64 + (size_t)q * 4096 + r * 4;
#pragma unroll 4
  for (int i = 0; i < 16; ++i) {
    const int l = wave * 16 + i;
    const float* rowb = basep + (size_t)l * tstride;
    float ax = 0.f, ay = 0.f, az = 0.f, aw = 0.f;
#pragma unroll
    for (int hb = 0; hb < 2; ++hb) {
      float4 v = *(const float4*)(rowb + (size_t)hb * 4 * 4096);
      float m = fmaxf(fmaxf(v.x, v.y), fmaxf(v.z, v.w));
#pragma unroll
      for (int mk = 1; mk <= 8; mk <<= 1) m = fmaxf(m, __shfl_xor(m, mk));
      float ex = expf(v.x - m), ey = expf(v.y - m), ez = expf(v.z - m), ew = expf(v.w - m);
      float sm = ex + ey + ez + ew;
#pragma unroll
      for (int mk = 1; mk <= 8; mk <<= 1) sm += __shfl_xor(sm, mk);
      float inv = 1.0f / sm;
      ax += ex * inv; ay += ey * inv; az += ez * inv; aw += ew * inv;
    }
#pragma unroll
    for (int mk = 16; mk <= 32; mk <<= 1) {
      ax += __shfl_xor(ax, mk); ay += __shfl_xor(ay, mk);
      az += __shfl_xor(az, mk); aw += __shfl_xor(aw, mk);
    }
    if (q == 0) {
      float4 ps = make_float4(ax * 0.125f, ay * 0.125f, az * 0.125f, aw * 0.125f);
      *(float4*)&Ps[l][r * 4] = ps;
    }
  }
  __syncthreads();

  // ---- phase 2a: per-l entropy and total-variation rows ----
#pragma unroll 1
  for (int i = 0; i < 16; ++i) {
    const int l = wave * 16 + i;
    float p = Ps[l][lane];
    float pc = fmaxf(p, EPSV);
    float entv = wsum64(pc * logf(pc));
    float dab = 0.f;
    if (l < 63) dab = fabsf(Ps[l + 1][lane] - p);
    float dsum = wsum64(dab);
    if (lane == 0) { ent_s[l] = -entv; diff_s[l] = dsum; }
  }

  // ---- phase 2b: per-j partial sums over this wave's l-range ----
  {
    float psum = 0.f, dsq = 0.f;
#pragma unroll 1
    for (int i = 0; i < 16; ++i) {
      const int l = wave * 16 + i;
      float p = Ps[l][lane];
      psum += p;
      if (l < 63) { float d = Ps[l + 1][lane] - p; dsq += d * d; }
    }
    psum_s[wave][lane] = psum;
    dsq_s[wave][lane] = dsq;
  }
  __syncthreads();

  // ---- phase 2c: edge features (wave 1) ----
  if (wave == 1) {
    const int j = lane;
    float tot = psum_s[0][j] + psum_s[1][j] + psum_s[2][j] + psum_s[3][j];
    float dsq = dsq_s[0][j] + dsq_s[1][j] + dsq_s[2][j] + dsq_s[3][j];
    float pem = tot * (1.0f / 64.0f);
    float dmean = (Ps[63][j] - Ps[0][j]) * (1.0f / 63.0f);
    float dvar = (dsq - 63.0f * dmean * dmean) * (1.0f / 62.0f);
    float dstd = sqrtf(fmaxf(dvar, 0.f));
    size_t eo = (size_t)bs * 4096 + (size_t)n * 64 + j;
    float4 ef = make_float4(pem, dstd, fmaxf(dmean, 0.f), fmaxf(-dmean, 0.f));
    *(float4*)(edge + eo * 4) = ef;
    score[eo] = (j == n) ? 0.f : fabsf(dmean);
  }

  // ---- phase 2d: node features (wave 0), two-pass variance ----
  if (wave == 0) {
    float e = ent_s[lane];
    float dg = Ps[lane][n];
    bool dv = lane < 63;
    float df = dv ? diff_s[lane] : 0.f;

    float esum = wsum64(e);
    float emax = wmax64(e);
    float emin = wmin64(e);
    float dgsum = wsum64(dg);
    float dfsum = wsum64(df);
    float dfmax = wmax64(dv ? df : -INFINITY);

    float emean = esum * (1.0f / 64.0f);
    float dgmean = dgsum * (1.0f / 64.0f);
    float dfmean = dfsum * (1.0f / 63.0f);

    float ed = e - emean;
    float evar = wsum64(ed * ed) * (1.0f / 63.0f);
    float dgd = dg - dgmean;
    float dgvar = wsum64(dgd * dgd) * (1.0f / 63.0f);
    float dfd = dv ? (df - dfmean) : 0.f;
    float dfvar = wsum64(dfd * dfd) * (1.0f / 62.0f);

    if (lane == 0) {
      float* no = node + ((size_t)bs * 64 + n) * 9;
      no[0] = emean;
      no[1] = sqrtf(fmaxf(evar, 0.f));
      no[2] = emax - emin;
      no[3] = (ent_s[63] - ent_s[0]) * (1.0f / 63.0f);
      no[4] = dfmean;
      no[5] = sqrtf(fmaxf(dfvar, 0.f));
      no[6] = dfmax;
      no[7] = dgmean;
      no[8] = sqrtf(fmaxf(dgvar, 0.f));
    }
  }
}

// One workgroup per (b, s): top-16 extraction + feat assembly.
__global__ __launch_bounds__(256) void stage2_kernel(
    const float* __restrict__ node, const float* __restrict__ edge,
    const float* __restrict__ score, float* __restrict__ feat) {
  const int bsid = blockIdx.x;  // b*4+s
  const int b = bsid >> 2, s = bsid & 3;
  __shared__ float sc[4096];
  __shared__ int widx[16];
  __shared__ float rv[4];
  __shared__ int ri[4];
  const int tid = threadIdx.x;
  const int wave = tid >> 6, lane = tid & 63;

  const float* scg = score + (size_t)bsid * 4096;
  for (int i = tid; i < 4096; i += 256) sc[i] = scg[i];
  __syncthreads();

  for (int k = 0; k < 16; ++k) {
    float bv = -1.f;
    int bi = 1 << 30;
    for (int i = tid; i < 4096; i += 256) {
      float v = sc[i];
      if (v > bv) { bv = v; bi = i; }
    }
#pragma unroll
    for (int mk = 1; mk <= 32; mk <<= 1) {
      float ov = __shfl_xor(bv, mk);
      int oi = __shfl_xor(bi, mk);
      if (ov > bv || (ov == bv && oi < bi)) { bv = ov; bi = oi; }
    }
    if (lane == 0) { rv[wave] = bv; ri[wave] = bi; }
    __syncthreads();
    if (tid == 0) {
      float fv = rv[0]; int fi = ri[0];
#pragma unroll
      for (int w = 1; w < 4; ++w)
        if (rv[w] > fv || (rv[w] == fv && ri[w] < fi)) { fv = rv[w]; fi = ri[w]; }
      widx[k] = fi;
      sc[fi] = -1.f;
    }
    __syncthreads();
  }

  float* fout = feat + (size_t)b * 2560 + s * 640;
  const float* nodeg = node + (size_t)bsid * 576;
  for (int i = tid; i < 576; i += 256) fout[i] = nodeg[i];
  if (tid < 16) {
    int idx = widx[tid];
    float4 ef = *(const float4*)(edge + ((size_t)bsid * 4096 + idx) * 4);
    *(float4*)(fout + 576 + tid * 4) = ef;
  }
}

// One workgroup per b: LayerNorm + MLP.
__global__ __launch_bounds__(256) void stage3_kernel(
    const float* __restrict__ feat, const float* __restrict__ gamma,
    const float* __restrict__ beta, const float* __restrict__ W1,
    const float* __restrict__ b1, const float* __restrict__ W2,
    const float* __restrict__ b2, float* __restrict__ out) {
  const int b = blockIdx.x;
  __shared__ float hf[2560];
  __shared__ float rs[4], rq[4];
  __shared__ float part[2][128];
  __shared__ float h1[128];
  __shared__ float part2[4][64];
  const int tid = threadIdx.x;
  const int wave = tid >> 6, lane = tid & 63;

  const float* f = feat + (size_t)b * 2560;
  float lsum = 0.f, lsq = 0.f;
  for (int i = tid; i < 2560; i += 256) {
    float v = f[i];
    hf[i] = v;
    lsum += v;
    lsq += v * v;
  }
  lsum = wsum64(lsum);
  lsq = wsum64(lsq);
  if (lane == 0) { rs[wave] = lsum; rq[wave] = lsq; }
  __syncthreads();
  float tsum = rs[0] + rs[1] + rs[2] + rs[3];
  float tsq = rq[0] + rq[1] + rq[2] + rq[3];
  float mean = tsum * (1.0f / 2560.0f);
  float var = tsq * (1.0f / 2560.0f) - mean * mean;
  float inv = rsqrtf(var + 1e-5f);
  for (int i = tid; i < 2560; i += 256)
    hf[i] = (hf[i] - mean) * inv * gamma[i] + beta[i];
  __syncthreads();

  {
    const int o = tid & 127, half = tid >> 7;
    float acc = 0.f;
    const int i0 = half * 1280;
    for (int i = i0; i < i0 + 1280; ++i) acc += hf[i] * W1[(size_t)i * 128 + o];
    part[half][o] = acc;
  }
  __syncthreads();
  if (tid < 128) h1[tid] = fmaxf(part[0][tid] + part[1][tid] + b1[tid], 0.f);
  __syncthreads();
  {
    const int o = tid & 63, pp = tid >> 6;
    float acc = 0.f;
    const int i0 = pp * 32;
    for (int i = i0; i < i0 + 32; ++i) acc += h1[i] * W2[i * 64 + o];
    part2[pp][o] = acc;
  }
  __syncthreads();
  if (tid < 64)
    out[(size_t)b * 64 + tid] =
        fmaxf(part2[0][tid] + part2[1][tid] + part2[2][tid] + part2[3][tid] + b2[tid], 0.f);
}

extern "C" void kernel_launch(void* const* d_in, const int* in_sizes, int n_in,
                              void* d_out, int out_size, void* d_ws, size_t ws_size,
                              hipStream_t stream) {
  const float* sat = (const float*)d_in[0];
  const float* gamma = (const float*)d_in[1];
  const float* beta = (const float*)d_in[2];
  const float* W1 = (const float*)d_in[3];
  const float* b1 = (const float*)d_in[4];
  const float* W2 = (const float*)d_in[5];
  const float* b2 = (const float*)d_in[6];
  float* out = (float*)d_out;

  float* ws = (float*)d_ws;
  float* edge = ws;                          // 16*4*4096*4 = 1048576 floats
  float* score = edge + 16 * 4 * 4096 * 4;   // 262144 floats
  float* node = score + 16 * 4 * 4096;       // 36864 floats
  float* feat = node + 16 * 4 * 64 * 9;      // 40960 floats

  stage1_kernel<<<4096, 256, 0, stream>>>(sat, node, edge, score);
  stage2_kernel<<<64, 256, 0, stream>>>(node, edge, score, feat);
  stage3_kernel<<<16, 256, 0, stream>>>(feat, gamma, beta, W1, b1, W2, b2, out);
}

// Round 2
// 199.085 us; speedup vs baseline: 1.1095x; 1.1095x over previous
//
#include <hip/hip_runtime.h>
#include <hip/hip_bf16.h>
#include <math.h>

#define EPSV 1e-8f

__device__ __forceinline__ float wsum64(float v) {
#pragma unroll
  for (int m = 1; m <= 32; m <<= 1) v += __shfl_xor(v, m);
  return v;
}
__device__ __forceinline__ float wmax64(float v) {
#pragma unroll
  for (int m = 1; m <= 32; m <<= 1) v = fmaxf(v, __shfl_xor(v, m));
  return v;
}
__device__ __forceinline__ float wmin64(float v) {
#pragma unroll
  for (int m = 1; m <= 32; m <<= 1) v = fminf(v, __shfl_xor(v, m));
  return v;
}

// One workgroup per (b, s, n): 4096 blocks x 256 threads.
// Row layout: 4 lanes per row (16 floats each, = one aligned 64-B line).
__global__ __launch_bounds__(256, 4) void stage1_kernel(
    const float* __restrict__ sat, float* __restrict__ node,
    float* __restrict__ edge, float* __restrict__ score) {
  const int bid = blockIdx.x;
  const int n = bid & 63;
  const int bs = bid >> 6;
  const int tbase = bs * 64;  // (b*4+s)*64 == b*256 + s*64

  __shared__ float Ps[64][64];
  __shared__ float ent_s[64];
  __shared__ float diff_s[64];
  __shared__ float psum_s[4][64];
  __shared__ float dsq_s[4][64];

  const int tid = threadIdx.x;
  const int wave = tid >> 6;
  const int lane = tid & 63;
  const int rsub = lane >> 2;   // row-in-wave 0..15
  const int chunk = lane & 3;   // 16-float chunk of the 64-float row
  const int l = wave * 16 + rsub;

  // ---- phase 1: softmax over j (64), mean over h (8) -> Ps[l][j] ----
  const float* rowb =
      sat + (size_t)(tbase + l) * 32768 + n * 64 + chunk * 16;

  float acc[16];
#pragma unroll
  for (int c = 0; c < 16; ++c) acc[c] = 0.f;

#pragma unroll 2
  for (int h = 0; h < 8; ++h) {
    const float* p = rowb + h * 4096;
    float r[16];
    *(float4*)&r[0]  = *(const float4*)(p);
    *(float4*)&r[4]  = *(const float4*)(p + 4);
    *(float4*)&r[8]  = *(const float4*)(p + 8);
    *(float4*)&r[12] = *(const float4*)(p + 12);
    float m = r[0];
#pragma unroll
    for (int c = 1; c < 16; ++c) m = fmaxf(m, r[c]);
    m = fmaxf(m, __shfl_xor(m, 1));
    m = fmaxf(m, __shfl_xor(m, 2));
    float s = 0.f;
#pragma unroll
    for (int c = 0; c < 16; ++c) { r[c] = __expf(r[c] - m); s += r[c]; }
    s += __shfl_xor(s, 1);
    s += __shfl_xor(s, 2);
    float inv = 1.0f / s;
#pragma unroll
    for (int c = 0; c < 16; ++c) acc[c] += r[c] * inv;
  }

  // entropy partial in-register (head-avg applied first)
  float ent = 0.f;
#pragma unroll
  for (int c = 0; c < 16; ++c) {
    acc[c] *= 0.125f;
    float pc = fmaxf(acc[c], EPSV);
    ent += pc * __logf(pc);
  }
  ent += __shfl_xor(ent, 1);
  ent += __shfl_xor(ent, 2);
  if (chunk == 0) ent_s[l] = -ent;

  *(float4*)&Ps[l][chunk * 16]      = make_float4(acc[0], acc[1], acc[2], acc[3]);
  *(float4*)&Ps[l][chunk * 16 + 4]  = make_float4(acc[4], acc[5], acc[6], acc[7]);
  *(float4*)&Ps[l][chunk * 16 + 8]  = make_float4(acc[8], acc[9], acc[10], acc[11]);
  *(float4*)&Ps[l][chunk * 16 + 12] = make_float4(acc[12], acc[13], acc[14], acc[15]);
  __syncthreads();

  // ---- phase 2a: per-j partial sums over this wave's 16 rows ----
  {
    float psum = 0.f, dsq = 0.f;
    float p = Ps[wave * 16][lane];
#pragma unroll 1
    for (int i = 0; i < 16; ++i) {
      const int ll = wave * 16 + i;
      psum += p;
      if (ll < 63) {
        float pn = Ps[ll + 1][lane];
        float d = pn - p;
        dsq += d * d;
        p = pn;
      }
    }
    psum_s[wave][lane] = psum;
    dsq_s[wave][lane] = dsq;
  }

  // ---- phase 2b: row sums of |dP| (total variation), 4 lanes/row ----
  {
    const int dl = tid >> 2, dpart = tid & 3;
    float dsum = 0.f;
    if (dl < 63) {
      const float4* r0 = (const float4*)&Ps[dl][dpart * 16];
      const float4* r1 = (const float4*)&Ps[dl + 1][dpart * 16];
#pragma unroll
      for (int c4 = 0; c4 < 4; ++c4) {
        float4 a = r0[c4], b = r1[c4];
        dsum += fabsf(b.x - a.x) + fabsf(b.y - a.y) +
                fabsf(b.z - a.z) + fabsf(b.w - a.w);
      }
    }
    dsum += __shfl_xor(dsum, 1);
    dsum += __shfl_xor(dsum, 2);
    if (dpart == 0 && dl < 63) diff_s[dl] = dsum;
  }
  __syncthreads();

  // ---- phase 2c: edge features (wave 1) ----
  if (wave == 1) {
    const int j = lane;
    float tot = psum_s[0][j] + psum_s[1][j] + psum_s[2][j] + psum_s[3][j];
    float dsq = dsq_s[0][j] + dsq_s[1][j] + dsq_s[2][j] + dsq_s[3][j];
    float pem = tot * (1.0f / 64.0f);
    float dmean = (Ps[63][j] - Ps[0][j]) * (1.0f / 63.0f);
    float dvar = (dsq - 63.0f * dmean * dmean) * (1.0f / 62.0f);
    float dstd = sqrtf(fmaxf(dvar, 0.f));
    size_t eo = (size_t)bs * 4096 + (size_t)n * 64 + j;
    float4 ef = make_float4(pem, dstd, fmaxf(dmean, 0.f), fmaxf(-dmean, 0.f));
    *(float4*)(edge + eo * 4) = ef;
    score[eo] = (j == n) ? 0.f : fabsf(dmean);
  }

  // ---- phase 2d: node features (wave 0), two-pass variance ----
  if (wave == 0) {
    float e = ent_s[lane];
    float dg = Ps[lane][n];
    bool dv = lane < 63;
    float df = dv ? diff_s[lane] : 0.f;

    float esum = wsum64(e);
    float emax = wmax64(e);
    float emin = wmin64(e);
    float dgsum = wsum64(dg);
    float dfsum = wsum64(df);
    float dfmax = wmax64(dv ? df : -INFINITY);

    float emean = esum * (1.0f / 64.0f);
    float dgmean = dgsum * (1.0f / 64.0f);
    float dfmean = dfsum * (1.0f / 63.0f);

    float ed = e - emean;
    float evar = wsum64(ed * ed) * (1.0f / 63.0f);
    float dgd = dg - dgmean;
    float dgvar = wsum64(dgd * dgd) * (1.0f / 63.0f);
    float dfd = dv ? (df - dfmean) : 0.f;
    float dfvar = wsum64(dfd * dfd) * (1.0f / 62.0f);

    if (lane == 0) {
      float* no = node + ((size_t)bs * 64 + n) * 9;
      no[0] = emean;
      no[1] = sqrtf(fmaxf(evar, 0.f));
      no[2] = emax - emin;
      no[3] = (ent_s[63] - ent_s[0]) * (1.0f / 63.0f);
      no[4] = dfmean;
      no[5] = sqrtf(fmaxf(dfvar, 0.f));
      no[6] = dfmax;
      no[7] = dgmean;
      no[8] = sqrtf(fmaxf(dgvar, 0.f));
    }
  }
}

// One workgroup per (b, s): top-16 extraction + feat assembly.
__global__ __launch_bounds__(256) void stage2_kernel(
    const float* __restrict__ node, const float* __restrict__ edge,
    const float* __restrict__ score, float* __restrict__ feat) {
  const int bsid = blockIdx.x;  // b*4+s
  const int b = bsid >> 2, s = bsid & 3;
  __shared__ float sc[4096];
  __shared__ int widx[16];
  __shared__ float rv[4];
  __shared__ int ri[4];
  const int tid = threadIdx.x;
  const int wave = tid >> 6, lane = tid & 63;

  const float* scg = score + (size_t)bsid * 4096;
  for (int i = tid; i < 4096; i += 256) sc[i] = scg[i];
  __syncthreads();

  for (int k = 0; k < 16; ++k) {
    float bv = -1.f;
    int bi = 1 << 30;
    for (int i = tid; i < 4096; i += 256) {
      float v = sc[i];
      if (v > bv) { bv = v; bi = i; }
    }
#pragma unroll
    for (int mk = 1; mk <= 32; mk <<= 1) {
      float ov = __shfl_xor(bv, mk);
      int oi = __shfl_xor(bi, mk);
      if (ov > bv || (ov == bv && oi < bi)) { bv = ov; bi = oi; }
    }
    if (lane == 0) { rv[wave] = bv; ri[wave] = bi; }
    __syncthreads();
    if (tid == 0) {
      float fv = rv[0]; int fi = ri[0];
#pragma unroll
      for (int w = 1; w < 4; ++w)
        if (rv[w] > fv || (rv[w] == fv && ri[w] < fi)) { fv = rv[w]; fi = ri[w]; }
      widx[k] = fi;
      sc[fi] = -1.f;
    }
    __syncthreads();
  }

  float* fout = feat + (size_t)b * 2560 + s * 640;
  const float* nodeg = node + (size_t)bsid * 576;
  for (int i = tid; i < 576; i += 256) fout[i] = nodeg[i];
  if (tid < 16) {
    int idx = widx[tid];
    float4 ef = *(const float4*)(edge + ((size_t)bsid * 4096 + idx) * 4);
    *(float4*)(fout + 576 + tid * 4) = ef;
  }
}

// One workgroup per b: LayerNorm + MLP.
__global__ __launch_bounds__(256) void stage3_kernel(
    const float* __restrict__ feat, const float* __restrict__ gamma,
    const float* __restrict__ beta, const float* __restrict__ W1,
    const float* __restrict__ b1, const float* __restrict__ W2,
    const float* __restrict__ b2, float* __restrict__ out) {
  const int b = blockIdx.x;
  __shared__ float hf[2560];
  __shared__ float rs[4], rq[4];
  __shared__ float part[2][128];
  __shared__ float h1[128];
  __shared__ float part2[4][64];
  const int tid = threadIdx.x;
  const int wave = tid >> 6, lane = tid & 63;

  const float* f = feat + (size_t)b * 2560;
  float lsum = 0.f, lsq = 0.f;
  for (int i = tid; i < 2560; i += 256) {
    float v = f[i];
    hf[i] = v;
    lsum += v;
    lsq += v * v;
  }
  lsum = wsum64(lsum);
  lsq = wsum64(lsq);
  if (lane == 0) { rs[wave] = lsum; rq[wave] = lsq; }
  __syncthreads();
  float tsum = rs[0] + rs[1] + rs[2] + rs[3];
  float tsq = rq[0] + rq[1] + rq[2] + rq[3];
  float mean = tsum * (1.0f / 2560.0f);
  float var = tsq * (1.0f / 2560.0f) - mean * mean;
  float inv = rsqrtf(var + 1e-5f);
  for (int i = tid; i < 2560; i += 256)
    hf[i] = (hf[i] - mean) * inv * gamma[i] + beta[i];
  __syncthreads();

  {
    const int o = tid & 127, half = tid >> 7;
    float acc = 0.f;
    const int i0 = half * 1280;
    for (int i = i0; i < i0 + 1280; ++i) acc += hf[i] * W1[(size_t)i * 128 + o];
    part[half][o] = acc;
  }
  __syncthreads();
  if (tid < 128) h1[tid] = fmaxf(part[0][tid] + part[1][tid] + b1[tid], 0.f);
  __syncthreads();
  {
    const int o = tid & 63, pp = tid >> 6;
    float acc = 0.f;
    const int i0 = pp * 32;
    for (int i = i0; i < i0 + 32; ++i) acc += h1[i] * W2[i * 64 + o];
    part2[pp][o] = acc;
  }
  __syncthreads();
  if (tid < 64)
    out[(size_t)b * 64 + tid] =
        fmaxf(part2[0][tid] + part2[1][tid] + part2[2][tid] + part2[3][tid] + b2[tid], 0.f);
}

extern "C" void kernel_launch(void* const* d_in, const int* in_sizes, int n_in,
                              void* d_out, int out_size, void* d_ws, size_t ws_size,
                              hipStream_t stream) {
  const float* sat = (const float*)d_in[0];
  const float* gamma = (const float*)d_in[1];
  const float* beta = (const float*)d_in[2];
  const float* W1 = (const float*)d_in[3];
  const float* b1 = (const float*)d_in[4];
  const float* W2 = (const float*)d_in[5];
  const float* b2 = (const float*)d_in[6];
  float* out = (float*)d_out;

  float* ws = (float*)d_ws;
  float* edge = ws;                          // 16*4*4096*4 = 1048576 floats
  float* score = edge + 16 * 4 * 4096 * 4;   // 262144 floats
  float* node = score + 16 * 4 * 4096;       // 36864 floats
  float* feat = node + 16 * 4 * 64 * 9;      // 40960 floats

  stage1_kernel<<<4096, 256, 0, stream>>>(sat, node, edge, score);
  stage2_kernel<<<64, 256, 0, stream>>>(node, edge, score, feat);
  stage3_kernel<<<16, 256, 0, stream>>>(feat, gamma, beta, W1, b1, W2, b2, out);
}